// Round 6
// baseline (62.164 us; speedup 1.0000x reference)
//
#include <hip/hip_runtime.h>

#define T_LEN    524288
#define BATCH    32
#define WIN      1024
#define STRIDE   256
#define NCODE    32
#define NFRAMES  2049
#define CHUNK    32               // frames per workgroup
#define NCHUNK   64               // chunks per batch row (frames 0..2047)
#define SPAN_F   8992             // (CHUNK-1)*256 + 1056 floats staged
#define NBLKC    35               // 256-sample blocks needed per chunk
#define BLSTR    36               // padded Bl row stride (16B-aligned, bank-spread)

typedef float f32x2 __attribute__((ext_vector_type(2)));

// XOR swizzle on LDS dword index: involution, keeps float4 chunks contiguous
// (only bits [4:2] change, driven by bits [7:5]^[10:8]). Spreads the stride-32
// (phase B) and stride-256 (phase C) read patterns to the minimal 8-dword/bank
// occupancy for ds_read_b128; max index stays < SPAN_F.
__device__ __forceinline__ int SW(int m) {
    return m ^ ((((m >> 5) ^ (m >> 8)) & 7) << 2);
}

// ---------------------------------------------------------------------------
// One workgroup: 32 frames of one batch row.
//  A: coalesced stage of 8992 floats (zero-fill past T) into swizzled LDS.
//  B: 35 block-products (lags 0..32) -> Bl[][]; 8 lanes per block, 32-sample
//     segments, v_pk_fma_f32-packed (r5-validated math), shfl_xor{1,2,4} reduce.
//     280 segments = 256 threads + 24-thread second round.
//  C: lanes 0..31 of wave 0: corr = 4 block sums + wrap correction, then the
//     r3-validated fully-unrolled Levinson-Durbin, float4 stores.
// ---------------------------------------------------------------------------
__global__ __launch_bounds__(256) void lpc_fused(const float* __restrict__ in,
                                                 float* __restrict__ out) {
    __shared__ float xs[SPAN_F];
    __shared__ float Bl[NBLKC * BLSTR];

    const int tid = threadIdx.x;
    const int c   = blockIdx.x;          // chunk
    const int b   = blockIdx.y;          // batch row
    const float* row = in + (size_t)b * T_LEN;
    const int base = c * (CHUNK * STRIDE);   // 8192 floats per chunk

    // ---- Phase A: stage (coalesced global, swizzled LDS) ----
    for (int idx = tid; idx < SPAN_F / 4; idx += 256) {
        const int m   = idx * 4;
        const int off = base + m;        // multiple of 4; T_LEN multiple of 4
        float4 v = make_float4(0.f, 0.f, 0.f, 0.f);
        if (off < T_LEN) v = *reinterpret_cast<const float4*>(row + off);
        *reinterpret_cast<float4*>(&xs[SW(m)]) = v;
    }
    __syncthreads();

    // ---- Phase B: block products ----
    auto do_segment = [&](int seg) {
        const int m0 = seg * 32;         // segment covers samples [m0, m0+32)
        f32x2 w2[32];                    // 64 floats: 32 own + 32 lookahead
        #pragma unroll
        for (int q = 0; q < 16; ++q) {
            const float4 v = *reinterpret_cast<const float4*>(&xs[SW(m0 + 4 * q)]);
            w2[2*q]   = f32x2{v.x, v.y};
            w2[2*q+1] = f32x2{v.z, v.w};
        }

        f32x2 accE[16], accO[16];
        #pragma unroll
        for (int t = 0; t < 16; ++t) { accE[t] = f32x2{0.f, 0.f}; accO[t] = f32x2{0.f, 0.f}; }
        float accE32 = 0.f, accO0 = 0.f;

        #pragma unroll
        for (int q = 0; q < 16; ++q) {
            #pragma unroll
            for (int t = 0; t < 16; ++t) {      // even j: lags (2t, 2t+1)
                asm("v_pk_fma_f32 %0, %1, %2, %0 op_sel:[0,0,0] op_sel_hi:[0,1,1]"
                    : "+v"(accE[t]) : "v"(w2[q]), "v"(w2[q + t]));
            }
            accE32 = fmaf(w2[q].x, w2[q + 16].x, accE32);
            #pragma unroll
            for (int t = 0; t < 16; ++t) {      // odd j: lags (2t+1, 2t+2)
                asm("v_pk_fma_f32 %0, %1, %2, %0 op_sel:[1,0,0] op_sel_hi:[1,1,1]"
                    : "+v"(accO[t]) : "v"(w2[q]), "v"(w2[q + t + 1]));
            }
            accO0 = fmaf(w2[q].y, w2[q].y, accO0);
        }

        float acc[NCODE + 1];
        acc[0] = accE[0].x + accO0;
        #pragma unroll
        for (int t = 0; t < 16; ++t) acc[2*t + 1] = accE[t].y + accO[t].x;
        #pragma unroll
        for (int t = 0; t < 15; ++t) acc[2*t + 2] = accE[t + 1].x + accO[t].y;
        acc[32] = accE32 + accO[15].y;

        // 8-lane reduce (segment lanes are consecutive, xor partners in-group)
        #pragma unroll
        for (int k = 0; k <= NCODE; ++k) {
            acc[k] += __shfl_xor(acc[k], 1, 64);
            acc[k] += __shfl_xor(acc[k], 2, 64);
            acc[k] += __shfl_xor(acc[k], 4, 64);
        }

        if ((seg & 7) == 0) {
            const int ib = seg >> 3;
            float* dst = &Bl[ib * BLSTR];
            #pragma unroll
            for (int k = 0; k <= NCODE; ++k) dst[k] = acc[k];
        }
    };

    do_segment(tid);                     // blocks 0..31
    if (tid < 24) do_segment(256 + tid); // blocks 32..34
    __syncthreads();

    // ---- Phase C: corr assembly + Levinson (lanes 0..31 of wave 0) ----
    if (tid < CHUNK) {
        const int fl = tid;
        const int o  = fl * STRIDE;      // frame start, chunk-local

        float F[NCODE + 1];
        #pragma unroll
        for (int k = 0; k <= NCODE; ++k) F[k] = 0.f;
        #pragma unroll
        for (int d = 0; d < 4; ++d) {
            const float* Bp = &Bl[(fl + d) * BLSTR];
            #pragma unroll
            for (int q = 0; q < 8; ++q) {
                const float4 v = *reinterpret_cast<const float4*>(Bp + 4 * q);
                F[4*q]   += v.x; F[4*q+1] += v.y;
                F[4*q+2] += v.z; F[4*q+3] += v.w;
            }
            F[32] += Bp[32];
        }

        float a[32], u[32], cx[32];
        #pragma unroll
        for (int q = 0; q < 8; ++q) {
            const float4 v = *reinterpret_cast<const float4*>(&xs[SW(o + 4 * q)]);
            a[4*q] = v.x; a[4*q+1] = v.y; a[4*q+2] = v.z; a[4*q+3] = v.w;
        }
        #pragma unroll
        for (int q = 0; q < 8; ++q) {
            const float4 v = *reinterpret_cast<const float4*>(&xs[SW(o + 992 + 4 * q)]);
            u[4*q] = v.x; u[4*q+1] = v.y; u[4*q+2] = v.z; u[4*q+3] = v.w;
        }
        #pragma unroll
        for (int q = 0; q < 8; ++q) {
            const float4 v = *reinterpret_cast<const float4*>(&xs[SW(o + 1024 + 4 * q)]);
            cx[4*q] = v.x; cx[4*q+1] = v.y; cx[4*q+2] = v.z; cx[4*q+3] = v.w;
        }

        float dd[32];
        #pragma unroll
        for (int j = 0; j < 32; ++j) dd[j] = a[j] - cx[j];

        float corr[NCODE + 1];
        corr[0] = F[0];
        #pragma unroll
        for (int k = 1; k <= NCODE; ++k) {
            float acc2 = F[k];
            #pragma unroll
            for (int j = 0; j < k; ++j) acc2 = fmaf(u[32 - k + j], dd[j], acc2);
            corr[k] = acc2;
        }

        // Levinson-Durbin (r3-validated), fully unrolled -> registers only.
        const float eps = 1e-7f;
        float sol[NCODE + 1];
        const float c0 = fmaxf(corr[0], eps);
        sol[0] = 1.0f;
        sol[1] = -corr[1] / c0;
        float extra = fmaf(corr[1], sol[1], corr[0]);

        #pragma unroll
        for (int k = 1; k < NCODE; ++k) {
            float dot = 0.f;
            #pragma unroll
            for (int i = 0; i <= k; ++i) dot = fmaf(sol[i], corr[k + 1 - i], dot);
            const float lam = -dot / fmaxf(extra, eps);

            float ns[NCODE + 1];
            #pragma unroll
            for (int j = 0; j <= k + 1; ++j) {
                const float av  = (j <= k) ? sol[j] : 0.f;
                const float rev = (j >= 1) ? sol[k + 1 - j] : 0.f;
                ns[j] = fmaf(lam, rev, av);
            }
            #pragma unroll
            for (int j = 0; j <= k + 1; ++j) sol[j] = ns[j];

            extra = (1.f - lam * lam) * extra;
        }

        float* op = out + ((size_t)b * NFRAMES + c * CHUNK + fl) * NCODE;
        #pragma unroll
        for (int i = 0; i < 8; ++i) {
            *reinterpret_cast<float4*>(op + 4 * i) =
                make_float4(sol[4*i + 1], sol[4*i + 2], sol[4*i + 3], sol[4*i + 4]);
        }
    } else if (tid == 32 && c == NCHUNK - 1) {
        // Frame 2048: window is entirely zero-pad -> corr = 0 -> coeffs = 0
        // (reference's eps-clamped path yields exact zeros; verified r0-r5 math).
        float* op = out + ((size_t)b * NFRAMES + 2048) * NCODE;
        #pragma unroll
        for (int i = 0; i < 8; ++i)
            *reinterpret_cast<float4*>(op + 4 * i) = make_float4(0.f, 0.f, 0.f, 0.f);
    }
}

// ---------------------------------------------------------------------------
extern "C" void kernel_launch(void* const* d_in, const int* in_sizes, int n_in,
                              void* d_out, int out_size, void* d_ws, size_t ws_size,
                              hipStream_t stream) {
    const float* in = (const float*)d_in[0];
    float* out      = (float*)d_out;

    dim3 grid(NCHUNK, BATCH);            // 64 x 32 = 2048 workgroups
    lpc_fused<<<grid, 256, 0, stream>>>(in, out);
}

// Round 7
// 44.904 us; speedup vs baseline: 1.3844x; 1.3844x over previous
//
#include <hip/hip_runtime.h>

#define T_LEN    524288
#define BATCH    32
#define WIN      1024
#define STRIDE   256
#define NCODE    32
#define NFRAMES  2049
#define NFR_TOT  (BATCH * NFRAMES)
#define NBLK     2048                // 256-sample product-blocks per row
#define NG       (BATCH * NBLK)     // 65536 blocks total
#define WGBLK    32                  // blocks per pass-1 workgroup
#define SPAN1    8224                // WGBLK*256 + 32 lookahead floats (32.9 KB)

typedef float f32x2 __attribute__((ext_vector_type(2)));

// XOR swizzle on LDS dword index (r6-validated): involution on bits [4:2]
// driven by [7:5]^[10:8]; keeps float4 quads contiguous; spreads the
// stride-128B phase-B read pattern across all 32 banks.
__device__ __forceinline__ int SW(int m) {
    return m ^ ((((m >> 5) ^ (m >> 8)) & 7) << 2);
}

// ---------------------------------------------------------------------------
// Pass 1 (v2): coalesced LDS staging + register lag products.
//   B[k*NG + g] = sum_{m=256i}^{256i+255} x[b,m]*x[b,m+k],  g = b*2048+i.
// Workgroup: 32 blocks of one row. Phase A: stage 8224 floats coalesced
// (each cache line requested once) into swizzled LDS. Phase B: thread t owns
// the 32-sample segment m0=32t: 16x ds_read_b128 (swizzled), 544 v_pk_fma_f32
// (r6-validated decomposition), shfl_xor{1,2,4} reduce, lag-plane stores.
// ---------------------------------------------------------------------------
__global__ __launch_bounds__(256) void blockprod_kernel(const float* __restrict__ in,
                                                        float* __restrict__ B) {
    __shared__ float xs[SPAN1];
    const int bx  = blockIdx.x;          // chunk of 32 blocks within the row
    const int by  = blockIdx.y;          // batch row
    const int tid = threadIdx.x;
    const float* row = in + (size_t)by * T_LEN;
    const int base = bx * (WGBLK * 256); // 8192 floats per chunk

    // ---- Phase A: coalesced stage, zero-fill past T (the reference pad) ----
    for (int idx = tid; idx < SPAN1 / 4; idx += 256) {
        const int m   = idx * 4;
        const int off = base + m;        // multiples of 4; no float4 straddle
        float4 v = make_float4(0.f, 0.f, 0.f, 0.f);
        if (off < T_LEN) v = *reinterpret_cast<const float4*>(row + off);
        *reinterpret_cast<float4*>(&xs[SW(m)]) = v;
    }
    __syncthreads();

    // ---- Phase B: one 32-sample segment per thread ----
    const int m0 = tid * 32;             // needs [m0, m0+64) <= 8224 ✓
    f32x2 w2[32];
    #pragma unroll
    for (int q = 0; q < 16; ++q) {
        const float4 v = *reinterpret_cast<const float4*>(&xs[SW(m0 + 4 * q)]);
        w2[2*q]   = f32x2{v.x, v.y};
        w2[2*q+1] = f32x2{v.z, v.w};
    }

    f32x2 accE[16], accO[16];
    #pragma unroll
    for (int t = 0; t < 16; ++t) { accE[t] = f32x2{0.f, 0.f}; accO[t] = f32x2{0.f, 0.f}; }
    float accE32 = 0.f, accO0 = 0.f;

    #pragma unroll
    for (int q = 0; q < 16; ++q) {
        #pragma unroll
        for (int t = 0; t < 16; ++t) {      // even j = 2q: lags (2t, 2t+1)
            asm("v_pk_fma_f32 %0, %1, %2, %0 op_sel:[0,0,0] op_sel_hi:[0,1,1]"
                : "+v"(accE[t]) : "v"(w2[q]), "v"(w2[q + t]));
        }
        accE32 = fmaf(w2[q].x, w2[q + 16].x, accE32);
        #pragma unroll
        for (int t = 0; t < 16; ++t) {      // odd j = 2q+1: lags (2t+1, 2t+2)
            asm("v_pk_fma_f32 %0, %1, %2, %0 op_sel:[1,0,0] op_sel_hi:[1,1,1]"
                : "+v"(accO[t]) : "v"(w2[q]), "v"(w2[q + t + 1]));
        }
        accO0 = fmaf(w2[q].y, w2[q].y, accO0);
    }

    float acc[NCODE + 1];
    acc[0] = accE[0].x + accO0;
    #pragma unroll
    for (int t = 0; t < 16; ++t) acc[2*t + 1] = accE[t].y + accO[t].x;
    #pragma unroll
    for (int t = 0; t < 15; ++t) acc[2*t + 2] = accE[t + 1].x + accO[t].y;
    acc[32] = accE32 + accO[15].y;

    #pragma unroll
    for (int k = 0; k <= NCODE; ++k) {      // 8-lane segment-group reduce
        acc[k] += __shfl_xor(acc[k], 1, 64);
        acc[k] += __shfl_xor(acc[k], 2, 64);
        acc[k] += __shfl_xor(acc[k], 4, 64);
    }

    if ((tid & 7) == 0) {
        const int g = by * NBLK + bx * WGBLK + (tid >> 3);
        #pragma unroll
        for (int k = 0; k <= NCODE; ++k) B[(size_t)k * NG + g] = acc[k];
    }
}

// ---------------------------------------------------------------------------
// Pass 2 (byte-identical to r5, validated): one thread per frame.
//   corr[k] = sum_{d<4} B[k][g0+d] + sum_{j<k} u[32-k+j]*(a[j]-c[j])
// then fully-unrolled Levinson-Durbin, float4 stores.
// ---------------------------------------------------------------------------
__global__ __launch_bounds__(256) void assemble_levinson_kernel(const float* __restrict__ in,
                                                                const float* __restrict__ B,
                                                                float* __restrict__ out) {
    const int t = blockIdx.x * 256 + threadIdx.x;
    if (t >= NFR_TOT) return;
    const int b = t / NFRAMES;
    const int f = t - b * NFRAMES;
    const float* row = in + (size_t)b * T_LEN;
    const int o = f * STRIDE;

    float F[NCODE + 1];
    #pragma unroll
    for (int k = 0; k <= NCODE; ++k) F[k] = 0.f;

    #pragma unroll
    for (int d = 0; d < 4; ++d) {
        const int i = f + d;
        if (i < NBLK) {
            const float* Bp = B + ((size_t)b * NBLK + i);
            #pragma unroll
            for (int k = 0; k <= NCODE; ++k) F[k] += Bp[(size_t)k * NG];
        }
    }

    float a[32], u[32], cx[32];
    auto ld4g = [&](int pos, float* dst) {
        float4 v = make_float4(0.f, 0.f, 0.f, 0.f);
        if (pos < T_LEN) v = *reinterpret_cast<const float4*>(row + pos);
        dst[0] = v.x; dst[1] = v.y; dst[2] = v.z; dst[3] = v.w;
    };
    #pragma unroll
    for (int q = 0; q < 8; ++q) ld4g(o + 4 * q,        &a[4 * q]);
    #pragma unroll
    for (int q = 0; q < 8; ++q) ld4g(o + 992 + 4 * q,  &u[4 * q]);
    #pragma unroll
    for (int q = 0; q < 8; ++q) ld4g(o + 1024 + 4 * q, &cx[4 * q]);

    float dd[32];
    #pragma unroll
    for (int j = 0; j < 32; ++j) dd[j] = a[j] - cx[j];

    float corr[NCODE + 1];
    corr[0] = F[0];
    #pragma unroll
    for (int k = 1; k <= NCODE; ++k) {
        float acc2 = F[k];
        #pragma unroll
        for (int j = 0; j < k; ++j) acc2 = fmaf(u[32 - k + j], dd[j], acc2);
        corr[k] = acc2;
    }

    const float eps = 1e-7f;
    float sol[NCODE + 1];
    const float c0 = fmaxf(corr[0], eps);
    sol[0] = 1.0f;
    sol[1] = -corr[1] / c0;
    float extra = fmaf(corr[1], sol[1], corr[0]);

    #pragma unroll
    for (int k = 1; k < NCODE; ++k) {
        float dot = 0.f;
        #pragma unroll
        for (int i = 0; i <= k; ++i) dot = fmaf(sol[i], corr[k + 1 - i], dot);
        const float lam = -dot / fmaxf(extra, eps);

        float ns[NCODE + 1];
        #pragma unroll
        for (int j = 0; j <= k + 1; ++j) {
            const float av  = (j <= k) ? sol[j] : 0.f;
            const float rev = (j >= 1) ? sol[k + 1 - j] : 0.f;
            ns[j] = fmaf(lam, rev, av);
        }
        #pragma unroll
        for (int j = 0; j <= k + 1; ++j) sol[j] = ns[j];

        extra = (1.f - lam * lam) * extra;
    }

    float* op = out + (size_t)t * NCODE;
    #pragma unroll
    for (int i = 0; i < 8; ++i) {
        *reinterpret_cast<float4*>(op + 4 * i) =
            make_float4(sol[4 * i + 1], sol[4 * i + 2],
                        sol[4 * i + 3], sol[4 * i + 4]);
    }
}

// ---------------------------------------------------------------------------
extern "C" void kernel_launch(void* const* d_in, const int* in_sizes, int n_in,
                              void* d_out, int out_size, void* d_ws, size_t ws_size,
                              hipStream_t stream) {
    const float* in = (const float*)d_in[0];
    float* out      = (float*)d_out;
    float* B        = (float*)d_ws;   // 33 * 65536 * 4 B = 8.65 MB

    dim3 g1(NBLK / WGBLK, BATCH);        // 64 x 32 workgroups
    blockprod_kernel<<<g1, 256, 0, stream>>>(in, B);
    assemble_levinson_kernel<<<(NFR_TOT + 255) / 256, 256, 0, stream>>>(in, B, out);
}